// Round 1
// baseline (11021.852 us; speedup 1.0000x reference)
//
#include <hip/hip_runtime.h>

#define NNODES 50000
#define NEDGES 800000

__device__ __forceinline__ float silu_f(float x) {
    return __fdividef(x, 1.0f + __expf(-x));
}

// ---------------- h0 = x0 @ lin1_w0 * l1 ; h1[n,v,m] = sum_u x1[n,u,m] lin1_w1[u,v] * l1
__global__ __launch_bounds__(128) void node_prep_kernel(
    const float* __restrict__ nf, const float* __restrict__ w0,
    const float* __restrict__ w1, float* __restrict__ h0, float* __restrict__ h1)
{
    __shared__ float row[128];
    const int n = blockIdx.x;
    const int j = threadIdx.x;
    row[j] = nf[n * 128 + j];
    __syncthreads();
    const float l1 = 0.17677669529663687f; // 1/sqrt(32)
    if (j < 32) {
        float acc = 0.0f;
        #pragma unroll
        for (int u = 0; u < 32; ++u) acc += row[u] * w0[u * 32 + j];
        h0[n * 32 + j] = acc * l1;
    } else {
        const int i = j - 32;
        const int v = i / 3;
        const int m = i - 3 * v;
        float acc = 0.0f;
        #pragma unroll
        for (int u = 0; u < 32; ++u) acc += row[32 + u * 3 + m] * w1[u * 32 + v];
        h1[n * 96 + i] = acc * l1;
    }
}

// ---------------- self-connection scalar+gate: sc_s/sc_g = einsum(nu,nv,uvw->nw)*scn
// wave-uniform half index h so weight addresses stay uniform (scalar loads)
__global__ __launch_bounds__(256) void sc_scalar_kernel(
    const float* __restrict__ nf, const float* __restrict__ za,
    const float* __restrict__ wS, const float* __restrict__ wG,
    float* __restrict__ scs, float* __restrict__ scg)
{
    const int t = blockIdx.x * 256 + threadIdx.x;
    const int lane = t & 63;
    const int h = (t >> 6) & 1;          // wave-uniform
    const int n = (t >> 7) * 64 + lane;
    if (n >= NNODES) return;
    const float* x0p = nf + n * 128;
    const float* zp  = za + n * 16;
    const float* bS0 = wS + h * 16;
    const float* bG0 = wG + h * 16;
    float accS[16], accG[16];
    #pragma unroll
    for (int w = 0; w < 16; ++w) { accS[w] = 0.0f; accG[w] = 0.0f; }
    for (int u = 0; u < 32; ++u) {
        const float xu = x0p[u];
        for (int v = 0; v < 16; ++v) {
            const float p = xu * zp[v];
            const float* bS = bS0 + (u * 16 + v) * 32;
            const float* bG = bG0 + (u * 16 + v) * 32;
            #pragma unroll
            for (int w = 0; w < 16; w += 4) {
                const float4 qs = *(const float4*)(bS + w);
                const float4 qg = *(const float4*)(bG + w);
                accS[w+0] += p * qs.x; accS[w+1] += p * qs.y;
                accS[w+2] += p * qs.z; accS[w+3] += p * qs.w;
                accG[w+0] += p * qg.x; accG[w+1] += p * qg.y;
                accG[w+2] += p * qg.z; accG[w+3] += p * qg.w;
            }
        }
    }
    const float scn = 0.04419417382415922f; // 1/sqrt(512)
    #pragma unroll
    for (int w = 0; w < 16; ++w) {
        scs[n * 32 + h * 16 + w] = accS[w] * scn;
        scg[n * 32 + h * 16 + w] = accG[w] * scn;
    }
}

// ---------------- self-connection vector: sc_v[n,w,m] = einsum(num,nv,uvw->nwm)*scn
__global__ __launch_bounds__(256) void sc_vec_kernel(
    const float* __restrict__ nf, const float* __restrict__ za,
    const float* __restrict__ wV, float* __restrict__ scv)
{
    const int t = blockIdx.x * 256 + threadIdx.x;
    if (t >= NNODES * 3) return;
    const int n = t / 3;
    const int m = t - 3 * n;
    const float* x1p = nf + n * 128 + 32 + m;
    const float* zp  = za + n * 16;
    float acc[32];
    #pragma unroll
    for (int w = 0; w < 32; ++w) acc[w] = 0.0f;
    for (int u = 0; u < 32; ++u) {
        const float xu = x1p[u * 3];
        for (int v = 0; v < 16; ++v) {
            const float p = xu * zp[v];
            const float* bV = wV + (u * 16 + v) * 32;  // uniform address
            #pragma unroll
            for (int w = 0; w < 32; w += 4) {
                const float4 q = *(const float4*)(bV + w);
                acc[w+0] += p * q.x; acc[w+1] += p * q.y;
                acc[w+2] += p * q.z; acc[w+3] += p * q.w;
            }
        }
    }
    const float scn = 0.04419417382415922f;
    #pragma unroll
    for (int w = 0; w < 32; ++w) scv[n * 96 + w * 3 + m] = acc[w] * scn;
}

// ---------------- per-edge: MLP (8->64->64->128), tensor product, atomic scatter
__global__ __launch_bounds__(128) void edge_kernel(
    const float* __restrict__ esh, const float* __restrict__ eemb,
    const float* __restrict__ fw0, const float* __restrict__ fw1,
    const float* __restrict__ fw2,
    const int* __restrict__ esrc, const int* __restrict__ edst,
    const float* __restrict__ h0, const float* __restrict__ h1,
    float* __restrict__ s0, float* __restrict__ s1)
{
    __shared__ float a2L[128 * 65];   // stride 65 -> (tid+j)%32 banks, conflict-free
    const int tid = threadIdx.x;
    const int e = blockIdx.x * 128 + tid;   // grid covers exactly 800000

    const float inv_s8 = 0.35355339059327373f; // 1/sqrt(8)
    float eb[8];
    {
        const float4 q0 = *(const float4*)(eemb + e * 8);
        const float4 q1 = *(const float4*)(eemb + e * 8 + 4);
        eb[0]=q0.x; eb[1]=q0.y; eb[2]=q0.z; eb[3]=q0.w;
        eb[4]=q1.x; eb[5]=q1.y; eb[6]=q1.z; eb[7]=q1.w;
    }
    float a1[64];
    #pragma unroll
    for (int g = 0; g < 16; ++g) {
        float c0=0.f,c1=0.f,c2=0.f,c3=0.f;
        #pragma unroll
        for (int j = 0; j < 8; ++j) {
            const float4 wv = *(const float4*)(fw0 + j * 64 + g * 4); // uniform
            const float a = eb[j];
            c0 += a*wv.x; c1 += a*wv.y; c2 += a*wv.z; c3 += a*wv.w;
        }
        a1[4*g+0] = silu_f(c0 * inv_s8);
        a1[4*g+1] = silu_f(c1 * inv_s8);
        a1[4*g+2] = silu_f(c2 * inv_s8);
        a1[4*g+3] = silu_f(c3 * inv_s8);
    }
    float* myA2 = &a2L[tid * 65];
    for (int g = 0; g < 16; ++g) {        // rolled: a2 goes to LDS (dynamic index ok)
        float c0=0.f,c1=0.f,c2=0.f,c3=0.f;
        #pragma unroll
        for (int j = 0; j < 64; ++j) {    // unrolled: a1[j] stays in registers
            const float4 wv = *(const float4*)(fw1 + j * 64 + g * 4); // uniform
            const float a = a1[j];
            c0 += a*wv.x; c1 += a*wv.y; c2 += a*wv.z; c3 += a*wv.w;
        }
        myA2[4*g+0] = silu_f(c0 * 0.125f);
        myA2[4*g+1] = silu_f(c1 * 0.125f);
        myA2[4*g+2] = silu_f(c2 * 0.125f);
        myA2[4*g+3] = silu_f(c3 * 0.125f);
    }
    const float4 sh = *(const float4*)(esh + e * 4);
    const float y0 = sh.x, y1x = sh.y, y1y = sh.z, y1z = sh.w;
    const int src = esrc[e];
    const int dst = edst[e];
    const float* h0p = h0 + src * 32;
    const float* h1p = h1 + src * 96;
    float* s0p = s0 + dst * 64;
    float* s1p = s1 + dst * 192;
    const float cs  = 0.125f * (1.0f / 16.0f);        // L3 scale * 1/N_NEIGH
    const float cs3 = cs * 0.5773502691896258f;       // * 1/sqrt(3)
    for (int g = 0; g < 8; ++g) {         // rolled: accumulators are scalars
        float w0a[4] = {0.f,0.f,0.f,0.f};
        float w1a[4] = {0.f,0.f,0.f,0.f};
        float w2a[4] = {0.f,0.f,0.f,0.f};
        float w3a[4] = {0.f,0.f,0.f,0.f};
        for (int j = 0; j < 64; ++j) {    // rolled: a2 from LDS
            const float a = myA2[j];
            const float* b2 = fw2 + j * 128 + g * 4;  // uniform
            const float4 q0 = *(const float4*)(b2);
            const float4 q1 = *(const float4*)(b2 + 32);
            const float4 q2 = *(const float4*)(b2 + 64);
            const float4 q3 = *(const float4*)(b2 + 96);
            w0a[0]+=a*q0.x; w0a[1]+=a*q0.y; w0a[2]+=a*q0.z; w0a[3]+=a*q0.w;
            w1a[0]+=a*q1.x; w1a[1]+=a*q1.y; w1a[2]+=a*q1.z; w1a[3]+=a*q1.w;
            w2a[0]+=a*q2.x; w2a[1]+=a*q2.y; w2a[2]+=a*q2.z; w2a[3]+=a*q2.w;
            w3a[0]+=a*q3.x; w3a[1]+=a*q3.y; w3a[2]+=a*q3.z; w3a[3]+=a*q3.w;
        }
        const float4 e0g = *(const float4*)(h0p + g * 4);
        const float e0a[4] = {e0g.x, e0g.y, e0g.z, e0g.w};
        const float4 f0 = *(const float4*)(h1p + g * 12);
        const float4 f1 = *(const float4*)(h1p + g * 12 + 4);
        const float4 f2 = *(const float4*)(h1p + g * 12 + 8);
        const float e1a[12] = {f0.x,f0.y,f0.z,f0.w,f1.x,f1.y,f1.z,f1.w,f2.x,f2.y,f2.z,f2.w};
        #pragma unroll
        for (int c = 0; c < 4; ++c) {
            const int u = g * 4 + c;
            const float e0u = e0a[c];
            const float ex = e1a[c*3+0], ey = e1a[c*3+1], ez = e1a[c*3+2];
            const float dot = ex*y1x + ey*y1y + ez*y1z;
            atomicAdd(s0p + u,      w0a[c] * cs * e0u * y0);
            atomicAdd(s0p + 32 + u, w3a[c] * cs3 * dot);
            const float t1 = w1a[c] * cs * e0u;
            atomicAdd(s1p + u*3 + 0, t1 * y1x);
            atomicAdd(s1p + u*3 + 1, t1 * y1y);
            atomicAdd(s1p + u*3 + 2, t1 * y1z);
            const float t2 = w2a[c] * cs * y0;
            atomicAdd(s1p + 96 + u*3 + 0, t2 * ex);
            atomicAdd(s1p + 96 + u*3 + 1, t2 * ey);
            atomicAdd(s1p + 96 + u*3 + 2, t2 * ez);
        }
    }
}

// ---------------- lin2 + gates + output assembly
__global__ __launch_bounds__(128) void final_kernel(
    const float* __restrict__ s0, const float* __restrict__ s1,
    const float* __restrict__ scs, const float* __restrict__ scg,
    const float* __restrict__ scv,
    const float* __restrict__ l2w0, const float* __restrict__ l2w1,
    float* __restrict__ out)
{
    __shared__ float s0L[64];
    __shared__ float s1L[192];
    __shared__ float gL[32];
    const int n = blockIdx.x;
    const int j = threadIdx.x;
    if (j < 64) s0L[j] = s0[n * 64 + j];
    for (int i = j; i < 192; i += 128) s1L[i] = s1[n * 192 + i];
    __syncthreads();
    const float l2 = 0.125f; // 1/sqrt(64)
    if (j < 32) {
        float acc = 0.0f;
        #pragma unroll
        for (int k = 0; k < 64; ++k) acc += s0L[k] * l2w0[k * 64 + 32 + j];
        gL[j] = silu_f(acc * l2 + scg[n * 32 + j]);
    }
    __syncthreads();
    if (j < 32) {
        float acc = 0.0f;
        #pragma unroll
        for (int k = 0; k < 64; ++k) acc += s0L[k] * l2w0[k * 64 + j];
        out[n * 128 + j] = silu_f(acc * l2 + scs[n * 32 + j]);
    } else {
        const int i = j - 32;
        const int v = i / 3;
        const int m = i - 3 * v;
        float acc = 0.0f;
        #pragma unroll
        for (int u = 0; u < 64; ++u) acc += s1L[u * 3 + m] * l2w1[u * 32 + v];
        out[n * 128 + 32 + i] = gL[v] * (acc * l2 + scv[n * 96 + i]);
    }
}

extern "C" void kernel_launch(void* const* d_in, const int* in_sizes, int n_in,
                              void* d_out, int out_size, void* d_ws, size_t ws_size,
                              hipStream_t stream) {
    const float* nf   = (const float*)d_in[0];
    const float* za   = (const float*)d_in[1];
    const float* esh  = (const float*)d_in[2];
    const float* eemb = (const float*)d_in[3];
    const float* l1w0 = (const float*)d_in[4];
    const float* l1w1 = (const float*)d_in[5];
    const float* fw0  = (const float*)d_in[6];
    const float* fw1  = (const float*)d_in[7];
    const float* fw2  = (const float*)d_in[8];
    const float* wS   = (const float*)d_in[9];
    const float* wG   = (const float*)d_in[10];
    const float* wV   = (const float*)d_in[11];
    const float* l2w0 = (const float*)d_in[12];
    const float* l2w1 = (const float*)d_in[13];
    const int* esrc   = (const int*)d_in[14];
    const int* edst   = (const int*)d_in[15];
    float* out = (float*)d_out;

    float* ws  = (float*)d_ws;
    float* h0  = ws;                 // 50000*32  = 1.6e6 floats
    float* h1  = h0 + 1600000;       // 50000*96  = 4.8e6
    float* s0  = h1 + 4800000;       // 50000*64  = 3.2e6 (accumulator)
    float* s1  = s0 + 3200000;       // 50000*192 = 9.6e6 (accumulator)
    float* scs = s1 + 9600000;       // 50000*32
    float* scg = scs + 1600000;      // 50000*32
    float* scv = scg + 1600000;      // 50000*96
    // total 27.2e6 floats = 108.8 MB

    hipMemsetAsync(s0, 0, (size_t)(3200000 + 9600000) * sizeof(float), stream);
    node_prep_kernel<<<NNODES, 128, 0, stream>>>(nf, l1w0, l1w1, h0, h1);
    sc_scalar_kernel<<<391, 256, 0, stream>>>(nf, za, wS, wG, scs, scg);
    sc_vec_kernel<<<586, 256, 0, stream>>>(nf, za, wV, scv);
    edge_kernel<<<6250, 128, 0, stream>>>(esh, eemb, fw0, fw1, fw2, esrc, edst, h0, h1, s0, s1);
    final_kernel<<<NNODES, 128, 0, stream>>>(s0, s1, scs, scg, scv, l2w0, l2w1, out);
}

// Round 2
// 1556.549 us; speedup vs baseline: 7.0810x; 7.0810x over previous
//
#include <hip/hip_runtime.h>

#define NNODES 50000
#define NEDGES 800000
#define NCHUNK 196   // ceil(50000/256)

__device__ __forceinline__ float silu_f(float x) {
    return __fdividef(x, 1.0f + __expf(-x));
}
__device__ __forceinline__ unsigned bf16rne(float x) {
    unsigned u = __float_as_uint(x);
    return (u + 0x7FFFu + ((u >> 16) & 1u)) >> 16;
}
__device__ __forceinline__ float bf2f(unsigned short h) {
    return __uint_as_float(((unsigned)h) << 16);
}

// ---------------- h0 = x0 @ lin1_w0 * l1 ; h1[n,v,m] = sum_u x1[n,u,m] lin1_w1[u,v] * l1
__global__ __launch_bounds__(128) void node_prep_kernel(
    const float* __restrict__ nf, const float* __restrict__ w0,
    const float* __restrict__ w1, float* __restrict__ h0, float* __restrict__ h1)
{
    __shared__ float row[128];
    const int n = blockIdx.x;
    const int j = threadIdx.x;
    row[j] = nf[n * 128 + j];
    __syncthreads();
    const float l1 = 0.17677669529663687f; // 1/sqrt(32)
    if (j < 32) {
        float acc = 0.0f;
        #pragma unroll
        for (int u = 0; u < 32; ++u) acc += row[u] * w0[u * 32 + j];
        h0[n * 32 + j] = acc * l1;
    } else {
        const int i = j - 32;
        const int v = i / 3;
        const int m = i - 3 * v;
        float acc = 0.0f;
        #pragma unroll
        for (int u = 0; u < 32; ++u) acc += row[32 + u * 3 + m] * w1[u * 32 + v];
        h1[n * 96 + i] = acc * l1;
    }
}

// ---------------- self-connection scalar+gate
__global__ __launch_bounds__(256) void sc_scalar_kernel(
    const float* __restrict__ nf, const float* __restrict__ za,
    const float* __restrict__ wS, const float* __restrict__ wG,
    float* __restrict__ scs, float* __restrict__ scg)
{
    const int t = blockIdx.x * 256 + threadIdx.x;
    const int lane = t & 63;
    const int h = (t >> 6) & 1;          // wave-uniform
    const int n = (t >> 7) * 64 + lane;
    if (n >= NNODES) return;
    const float* x0p = nf + n * 128;
    const float* zp  = za + n * 16;
    const float* bS0 = wS + h * 16;
    const float* bG0 = wG + h * 16;
    float accS[16], accG[16];
    #pragma unroll
    for (int w = 0; w < 16; ++w) { accS[w] = 0.0f; accG[w] = 0.0f; }
    for (int u = 0; u < 32; ++u) {
        const float xu = x0p[u];
        for (int v = 0; v < 16; ++v) {
            const float p = xu * zp[v];
            const float* bS = bS0 + (u * 16 + v) * 32;
            const float* bG = bG0 + (u * 16 + v) * 32;
            #pragma unroll
            for (int w = 0; w < 16; w += 4) {
                const float4 qs = *(const float4*)(bS + w);
                const float4 qg = *(const float4*)(bG + w);
                accS[w+0] += p * qs.x; accS[w+1] += p * qs.y;
                accS[w+2] += p * qs.z; accS[w+3] += p * qs.w;
                accG[w+0] += p * qg.x; accG[w+1] += p * qg.y;
                accG[w+2] += p * qg.z; accG[w+3] += p * qg.w;
            }
        }
    }
    const float scn = 0.04419417382415922f; // 1/sqrt(512)
    #pragma unroll
    for (int w = 0; w < 16; ++w) {
        scs[n * 32 + h * 16 + w] = accS[w] * scn;
        scg[n * 32 + h * 16 + w] = accG[w] * scn;
    }
}

// ---------------- self-connection vector
__global__ __launch_bounds__(256) void sc_vec_kernel(
    const float* __restrict__ nf, const float* __restrict__ za,
    const float* __restrict__ wV, float* __restrict__ scv)
{
    const int t = blockIdx.x * 256 + threadIdx.x;
    if (t >= NNODES * 3) return;
    const int n = t / 3;
    const int m = t - 3 * n;
    const float* x1p = nf + n * 128 + 32 + m;
    const float* zp  = za + n * 16;
    float acc[32];
    #pragma unroll
    for (int w = 0; w < 32; ++w) acc[w] = 0.0f;
    for (int u = 0; u < 32; ++u) {
        const float xu = x1p[u * 3];
        for (int v = 0; v < 16; ++v) {
            const float p = xu * zp[v];
            const float* bV = wV + (u * 16 + v) * 32;  // uniform address
            #pragma unroll
            for (int w = 0; w < 32; w += 4) {
                const float4 q = *(const float4*)(bV + w);
                acc[w+0] += p * q.x; acc[w+1] += p * q.y;
                acc[w+2] += p * q.z; acc[w+3] += p * q.w;
            }
        }
    }
    const float scn = 0.04419417382415922f;
    #pragma unroll
    for (int w = 0; w < 32; ++w) scv[n * 96 + w * 3 + m] = acc[w] * scn;
}

// ---------------- CSR build ----------------
__global__ __launch_bounds__(256) void hist_kernel(const int* __restrict__ edst,
                                                   int* __restrict__ cnt) {
    const int e = blockIdx.x * 256 + threadIdx.x;
    if (e < NEDGES) atomicAdd(&cnt[edst[e]], 1);
}

__global__ __launch_bounds__(256) void scan_a_kernel(const int* __restrict__ cnt,
                                                     int* __restrict__ bsum) {
    __shared__ int s[256];
    const int t = threadIdx.x;
    const int idx = blockIdx.x * 256 + t;
    s[t] = (idx < NNODES) ? cnt[idx] : 0;
    __syncthreads();
    for (int off = 128; off > 0; off >>= 1) {
        if (t < off) s[t] += s[t + off];
        __syncthreads();
    }
    if (t == 0) bsum[blockIdx.x] = s[0];
}

__global__ __launch_bounds__(256) void scan_b_kernel(const int* __restrict__ bsum,
                                                     int* __restrict__ boff) {
    __shared__ int s[256];
    const int t = threadIdx.x;
    const int v = (t < NCHUNK) ? bsum[t] : 0;
    s[t] = v;
    __syncthreads();
    for (int off = 1; off < 256; off <<= 1) {
        int x = (t >= off) ? s[t - off] : 0;
        __syncthreads();
        s[t] += x;
        __syncthreads();
    }
    if (t < NCHUNK) boff[t] = s[t] - v;   // exclusive
}

__global__ __launch_bounds__(256) void scan_c_kernel(const int* __restrict__ cnt,
                                                     const int* __restrict__ boff,
                                                     int* __restrict__ rowstart,
                                                     int* __restrict__ cur) {
    __shared__ int s[256];
    const int t = threadIdx.x;
    const int idx = blockIdx.x * 256 + t;
    const int v = (idx < NNODES) ? cnt[idx] : 0;
    s[t] = v;
    __syncthreads();
    for (int off = 1; off < 256; off <<= 1) {
        int x = (t >= off) ? s[t - off] : 0;
        __syncthreads();
        s[t] += x;
        __syncthreads();
    }
    if (idx < NNODES) {
        const int excl = s[t] - v + boff[blockIdx.x];
        rowstart[idx] = excl;
        cur[idx] = excl;
    }
}

__global__ __launch_bounds__(256) void fill_kernel(const int* __restrict__ edst,
                                                   int* __restrict__ cur,
                                                   int* __restrict__ eid) {
    const int e = blockIdx.x * 256 + threadIdx.x;
    if (e < NEDGES) {
        const int p = atomicAdd(&cur[edst[e]], 1);
        eid[p] = e;
    }
}

// ---------------- per-edge MLP (8->64->64->128), result stored bf16 ----------------
__global__ __launch_bounds__(128) void edge_mlp_kernel(
    const float* __restrict__ eemb,
    const float* __restrict__ fw0, const float* __restrict__ fw1,
    const float* __restrict__ fw2,
    unsigned short* __restrict__ wbuf)
{
    __shared__ float a2L[128 * 65];   // stride 65 -> conflict-free per-thread rows
    const int tid = threadIdx.x;
    const int e = blockIdx.x * 128 + tid;   // grid covers exactly 800000

    const float inv_s8 = 0.35355339059327373f; // 1/sqrt(8)
    float eb[8];
    {
        const float4 q0 = *(const float4*)(eemb + e * 8);
        const float4 q1 = *(const float4*)(eemb + e * 8 + 4);
        eb[0]=q0.x; eb[1]=q0.y; eb[2]=q0.z; eb[3]=q0.w;
        eb[4]=q1.x; eb[5]=q1.y; eb[6]=q1.z; eb[7]=q1.w;
    }
    float a1[64];
    #pragma unroll
    for (int g = 0; g < 16; ++g) {
        float c0=0.f,c1=0.f,c2=0.f,c3=0.f;
        #pragma unroll
        for (int j = 0; j < 8; ++j) {
            const float4 wv = *(const float4*)(fw0 + j * 64 + g * 4); // uniform
            const float a = eb[j];
            c0 += a*wv.x; c1 += a*wv.y; c2 += a*wv.z; c3 += a*wv.w;
        }
        a1[4*g+0] = silu_f(c0 * inv_s8);
        a1[4*g+1] = silu_f(c1 * inv_s8);
        a1[4*g+2] = silu_f(c2 * inv_s8);
        a1[4*g+3] = silu_f(c3 * inv_s8);
    }
    float* myA2 = &a2L[tid * 65];
    for (int g = 0; g < 16; ++g) {        // rolled: a2 in LDS
        float c0=0.f,c1=0.f,c2=0.f,c3=0.f;
        #pragma unroll
        for (int j = 0; j < 64; ++j) {    // unrolled: a1 stays in registers
            const float4 wv = *(const float4*)(fw1 + j * 64 + g * 4); // uniform
            const float a = a1[j];
            c0 += a*wv.x; c1 += a*wv.y; c2 += a*wv.z; c3 += a*wv.w;
        }
        myA2[4*g+0] = silu_f(c0 * 0.125f);
        myA2[4*g+1] = silu_f(c1 * 0.125f);
        myA2[4*g+2] = silu_f(c2 * 0.125f);
        myA2[4*g+3] = silu_f(c3 * 0.125f);
    }
    // layer 3: w = a2 @ fc_w2 * 0.125, store bf16
    unsigned short* wrow = wbuf + (size_t)e * 128;
    for (int g = 0; g < 32; ++g) {
        float c0=0.f,c1=0.f,c2=0.f,c3=0.f;
        for (int j = 0; j < 64; ++j) {
            const float a = myA2[j];
            const float4 wv = *(const float4*)(fw2 + j * 128 + g * 4); // uniform
            c0 += a*wv.x; c1 += a*wv.y; c2 += a*wv.z; c3 += a*wv.w;
        }
        uint2 p;
        p.x = bf16rne(c0 * 0.125f) | (bf16rne(c1 * 0.125f) << 16);
        p.y = bf16rne(c2 * 0.125f) | (bf16rne(c3 * 0.125f) << 16);
        *(uint2*)(wrow + g * 4) = p;
    }
}

// ---------------- gather + tensor product + lin2 + gate + output ----------------
__global__ __launch_bounds__(256) void gather_final_kernel(
    const float* __restrict__ esh, const int* __restrict__ esrc,
    const int* __restrict__ eid, const int* __restrict__ rowstart,
    const int* __restrict__ cnt, const unsigned short* __restrict__ wbuf,
    const float* __restrict__ h0, const float* __restrict__ h1,
    const float* __restrict__ scs, const float* __restrict__ scg,
    const float* __restrict__ scv,
    const float* __restrict__ l2w0, const float* __restrict__ l2w1,
    float* __restrict__ out)
{
    __shared__ float wL[8][128];
    __shared__ float hL[8][128];   // [0:32) = h0[src], [32:128) = h1[src]
    __shared__ float yL[8][4];
    __shared__ int   eL[8];
    __shared__ float sV[256];
    __shared__ float gL[32];

    const int n = blockIdx.x;
    const int j = threadIdx.x;
    const int start = rowstart[n];
    const int deg = cnt[n];

    // per-thread component mapping (computed once)
    int cls, u = 0, m = 0;
    if (j < 32)        { cls = 0; u = j; }
    else if (j < 64)   { cls = 1; u = j - 32; }
    else if (j < 160)  { cls = 2; const int i = j - 64;  u = i / 3; m = i - 3 * u; }
    else               { cls = 3; const int i = j - 160; u = i / 3; m = i - 3 * u; }

    float acc = 0.0f;
    for (int base = 0; base < deg; base += 8) {
        const int nk = min(8, deg - base);
        __syncthreads();          // protect LDS from previous iteration's readers
        if (j < nk) {
            const int ek = eid[start + base + j];
            eL[j] = ek;
            *(float4*)yL[j] = *(const float4*)(esh + ek * 4);
        }
        __syncthreads();
        {   // bulk stage: 256 threads x 4 elements = 1024 = 8 edges x 128
            const int i4 = j * 4;
            const int k = i4 >> 7;
            const int c = i4 & 127;
            if (k < nk) {
                const int ek = eL[k];
                const ushort4 wv = *(const ushort4*)(wbuf + (size_t)ek * 128 + c);
                wL[k][c+0] = bf2f(wv.x); wL[k][c+1] = bf2f(wv.y);
                wL[k][c+2] = bf2f(wv.z); wL[k][c+3] = bf2f(wv.w);
                const int src = esrc[ek];
                const float4 hv = (c < 32) ? *(const float4*)(h0 + src * 32 + c)
                                           : *(const float4*)(h1 + src * 96 + (c - 32));
                *(float4*)&hL[k][c] = hv;
            }
        }
        __syncthreads();
        if (cls == 0) {
            for (int k = 0; k < nk; ++k)
                acc += wL[k][u] * hL[k][u] * yL[k][0];
        } else if (cls == 1) {
            for (int k = 0; k < nk; ++k) {
                const float d = hL[k][32 + u*3 + 0] * yL[k][1]
                              + hL[k][32 + u*3 + 1] * yL[k][2]
                              + hL[k][32 + u*3 + 2] * yL[k][3];
                acc += wL[k][96 + u] * d;
            }
        } else if (cls == 2) {
            for (int k = 0; k < nk; ++k)
                acc += wL[k][32 + u] * hL[k][u] * yL[k][1 + m];
        } else {
            for (int k = 0; k < nk; ++k)
                acc += wL[k][64 + u] * yL[k][0] * hL[k][32 + u*3 + m];
        }
    }
    __syncthreads();
    const float cs  = 0.0625f;                 // 1/N_NEIGH
    const float cs3 = 0.03608439182435161f;    // cs / sqrt(3)
    sV[j] = acc * ((cls == 1) ? cs3 : cs);
    __syncthreads();

    // lin2 + gates + output  (sV[0:64) = s0, sV[64 + u*3 + m] = s1[u,m])
    const float l2 = 0.125f; // 1/sqrt(64)
    if (j < 32) {
        float a = 0.0f;
        #pragma unroll
        for (int k = 0; k < 64; ++k) a += sV[k] * l2w0[k * 64 + 32 + j];
        gL[j] = silu_f(a * l2 + scg[n * 32 + j]);
    }
    __syncthreads();
    if (j < 32) {
        float a = 0.0f;
        #pragma unroll
        for (int k = 0; k < 64; ++k) a += sV[k] * l2w0[k * 64 + j];
        out[n * 128 + j] = silu_f(a * l2 + scs[n * 32 + j]);
    } else if (j < 128) {
        const int i = j - 32;
        const int v = i / 3;
        const int mm = i - 3 * v;
        float a = 0.0f;
        #pragma unroll
        for (int uu = 0; uu < 64; ++uu) a += sV[64 + uu * 3 + mm] * l2w1[uu * 32 + v];
        out[n * 128 + 32 + i] = gL[v] * (a * l2 + scv[n * 96 + i]);
    }
}

extern "C" void kernel_launch(void* const* d_in, const int* in_sizes, int n_in,
                              void* d_out, int out_size, void* d_ws, size_t ws_size,
                              hipStream_t stream) {
    const float* nf   = (const float*)d_in[0];
    const float* za   = (const float*)d_in[1];
    const float* esh  = (const float*)d_in[2];
    const float* eemb = (const float*)d_in[3];
    const float* l1w0 = (const float*)d_in[4];
    const float* l1w1 = (const float*)d_in[5];
    const float* fw0  = (const float*)d_in[6];
    const float* fw1  = (const float*)d_in[7];
    const float* fw2  = (const float*)d_in[8];
    const float* wS   = (const float*)d_in[9];
    const float* wG   = (const float*)d_in[10];
    const float* wV   = (const float*)d_in[11];
    const float* l2w0 = (const float*)d_in[12];
    const float* l2w1 = (const float*)d_in[13];
    const int* esrc   = (const int*)d_in[14];
    const int* edst   = (const int*)d_in[15];
    float* out = (float*)d_out;

    float* ws  = (float*)d_ws;
    float* h0  = ws;                     // 1,600,000 floats
    float* h1  = h0 + 1600000;           // 4,800,000
    float* scs = h1 + 4800000;           // 1,600,000
    float* scg = scs + 1600000;          // 1,600,000
    float* scv = scg + 1600000;          // 4,800,000
    int*   cnt      = (int*)(scv + 4800000); // 50176
    int*   rowstart = cnt + 50176;           // 50176
    int*   cur      = rowstart + 50176;      // 50176
    int*   bsum     = cur + 50176;           // 256
    int*   boff     = bsum + 256;            // 256
    int*   eid      = boff + 256;            // 800,000
    unsigned short* wbuf = (unsigned short*)(eid + 800000); // 800000*128 bf16 = 204.8 MB
    // total ~266 MB of d_ws

    hipMemsetAsync(cnt, 0, 50176 * sizeof(int), stream);
    node_prep_kernel<<<NNODES, 128, 0, stream>>>(nf, l1w0, l1w1, h0, h1);
    sc_scalar_kernel<<<391, 256, 0, stream>>>(nf, za, wS, wG, scs, scg);
    sc_vec_kernel<<<586, 256, 0, stream>>>(nf, za, wV, scv);
    hist_kernel<<<3125, 256, 0, stream>>>(edst, cnt);
    scan_a_kernel<<<NCHUNK, 256, 0, stream>>>(cnt, bsum);
    scan_b_kernel<<<1, 256, 0, stream>>>(bsum, boff);
    scan_c_kernel<<<NCHUNK, 256, 0, stream>>>(cnt, boff, rowstart, cur);
    fill_kernel<<<3125, 256, 0, stream>>>(edst, cur, eid);
    edge_mlp_kernel<<<6250, 128, 0, stream>>>(eemb, fw0, fw1, fw2, wbuf);
    gather_final_kernel<<<NNODES, 256, 0, stream>>>(esh, esrc, eid, rowstart, cnt,
                                                    wbuf, h0, h1, scs, scg, scv,
                                                    l2w0, l2w1, out);
}

// Round 4
// 884.237 us; speedup vs baseline: 12.4648x; 1.7603x over previous
//
#include <hip/hip_runtime.h>

#define NNODES 50000
#define NEDGES 800000
#define NCHUNK 196   // ceil(50000/256)

typedef __attribute__((ext_vector_type(8))) short short8;
typedef __attribute__((ext_vector_type(4))) float f32x4;

__device__ __forceinline__ float silu_f(float x) {
    return __fdividef(x, 1.0f + __expf(-x));
}
__device__ __forceinline__ unsigned bf16rne(float x) {
    unsigned u = __float_as_uint(x);
    return (u + 0x7FFFu + ((u >> 16) & 1u)) >> 16;
}
__device__ __forceinline__ float bf2f(unsigned short h) {
    return __uint_as_float(((unsigned)h) << 16);
}

// ---------------- h0 = x0 @ lin1_w0 * l1 ; h1[n,v,m] = sum_u x1[n,u,m] lin1_w1[u,v] * l1
__global__ __launch_bounds__(128) void node_prep_kernel(
    const float* __restrict__ nf, const float* __restrict__ w0,
    const float* __restrict__ w1, float* __restrict__ h0, float* __restrict__ h1)
{
    __shared__ float row[128];
    const int n = blockIdx.x;
    const int j = threadIdx.x;
    row[j] = nf[n * 128 + j];
    __syncthreads();
    const float l1 = 0.17677669529663687f; // 1/sqrt(32)
    if (j < 32) {
        float acc = 0.0f;
        #pragma unroll
        for (int u = 0; u < 32; ++u) acc += row[u] * w0[u * 32 + j];
        h0[n * 32 + j] = acc * l1;
    } else {
        const int i = j - 32;
        const int v = i / 3;
        const int m = i - 3 * v;
        float acc = 0.0f;
        #pragma unroll
        for (int u = 0; u < 32; ++u) acc += row[32 + u * 3 + m] * w1[u * 32 + v];
        h1[n * 96 + i] = acc * l1;
    }
}

// ---------------- self-connection scalar+gate
__global__ __launch_bounds__(256) void sc_scalar_kernel(
    const float* __restrict__ nf, const float* __restrict__ za,
    const float* __restrict__ wS, const float* __restrict__ wG,
    float* __restrict__ scs, float* __restrict__ scg)
{
    const int t = blockIdx.x * 256 + threadIdx.x;
    const int lane = t & 63;
    const int h = __builtin_amdgcn_readfirstlane((t >> 6) & 1);  // wave-uniform -> s_load weights
    const int n = (t >> 7) * 64 + lane;
    if (n >= NNODES) return;
    const float* x0p = nf + n * 128;
    const float* zp  = za + n * 16;
    const float* bS0 = wS + h * 16;
    const float* bG0 = wG + h * 16;
    float accS[16], accG[16];
    #pragma unroll
    for (int w = 0; w < 16; ++w) { accS[w] = 0.0f; accG[w] = 0.0f; }
    for (int u = 0; u < 32; ++u) {
        const float xu = x0p[u];
        for (int v = 0; v < 16; ++v) {
            const float p = xu * zp[v];
            const float* bS = bS0 + (u * 16 + v) * 32;
            const float* bG = bG0 + (u * 16 + v) * 32;
            #pragma unroll
            for (int w = 0; w < 16; w += 4) {
                const float4 qs = *(const float4*)(bS + w);
                const float4 qg = *(const float4*)(bG + w);
                accS[w+0] += p * qs.x; accS[w+1] += p * qs.y;
                accS[w+2] += p * qs.z; accS[w+3] += p * qs.w;
                accG[w+0] += p * qg.x; accG[w+1] += p * qg.y;
                accG[w+2] += p * qg.z; accG[w+3] += p * qg.w;
            }
        }
    }
    const float scn = 0.04419417382415922f; // 1/sqrt(512)
    #pragma unroll
    for (int w = 0; w < 16; ++w) {
        scs[n * 32 + h * 16 + w] = accS[w] * scn;
        scg[n * 32 + h * 16 + w] = accG[w] * scn;
    }
}

// ---------------- self-connection vector
__global__ __launch_bounds__(256) void sc_vec_kernel(
    const float* __restrict__ nf, const float* __restrict__ za,
    const float* __restrict__ wV, float* __restrict__ scv)
{
    const int t = blockIdx.x * 256 + threadIdx.x;
    if (t >= NNODES * 3) return;
    const int n = t / 3;
    const int m = t - 3 * n;
    const float* x1p = nf + n * 128 + 32 + m;
    const float* zp  = za + n * 16;
    float acc[32];
    #pragma unroll
    for (int w = 0; w < 32; ++w) acc[w] = 0.0f;
    for (int u = 0; u < 32; ++u) {
        const float xu = x1p[u * 3];
        for (int v = 0; v < 16; ++v) {
            const float p = xu * zp[v];
            const float* bV = wV + (u * 16 + v) * 32;  // uniform address
            #pragma unroll
            for (int w = 0; w < 32; w += 4) {
                const float4 q = *(const float4*)(bV + w);
                acc[w+0] += p * q.x; acc[w+1] += p * q.y;
                acc[w+2] += p * q.z; acc[w+3] += p * q.w;
            }
        }
    }
    const float scn = 0.04419417382415922f;
    #pragma unroll
    for (int w = 0; w < 32; ++w) scv[n * 96 + w * 3 + m] = acc[w] * scn;
}

// ---------------- CSR build ----------------
__global__ __launch_bounds__(256) void hist_kernel(const int* __restrict__ edst,
                                                   int* __restrict__ cnt) {
    const int e = blockIdx.x * 256 + threadIdx.x;
    if (e < NEDGES) atomicAdd(&cnt[edst[e]], 1);
}

__global__ __launch_bounds__(256) void scan_a_kernel(const int* __restrict__ cnt,
                                                     int* __restrict__ bsum) {
    __shared__ int s[256];
    const int t = threadIdx.x;
    const int idx = blockIdx.x * 256 + t;
    s[t] = (idx < NNODES) ? cnt[idx] : 0;
    __syncthreads();
    for (int off = 128; off > 0; off >>= 1) {
        if (t < off) s[t] += s[t + off];
        __syncthreads();
    }
    if (t == 0) bsum[blockIdx.x] = s[0];
}

__global__ __launch_bounds__(256) void scan_b_kernel(const int* __restrict__ bsum,
                                                     int* __restrict__ boff) {
    __shared__ int s[256];
    const int t = threadIdx.x;
    const int v = (t < NCHUNK) ? bsum[t] : 0;
    s[t] = v;
    __syncthreads();
    for (int off = 1; off < 256; off <<= 1) {
        int x = (t >= off) ? s[t - off] : 0;
        __syncthreads();
        s[t] += x;
        __syncthreads();
    }
    if (t < NCHUNK) boff[t] = s[t] - v;   // exclusive
}

__global__ __launch_bounds__(256) void scan_c_kernel(const int* __restrict__ cnt,
                                                     const int* __restrict__ boff,
                                                     int* __restrict__ rowstart,
                                                     int* __restrict__ cur) {
    __shared__ int s[256];
    const int t = threadIdx.x;
    const int idx = blockIdx.x * 256 + t;
    const int v = (idx < NNODES) ? cnt[idx] : 0;
    s[t] = v;
    __syncthreads();
    for (int off = 1; off < 256; off <<= 1) {
        int x = (t >= off) ? s[t - off] : 0;
        __syncthreads();
        s[t] += x;
        __syncthreads();
    }
    if (idx < NNODES) {
        const int excl = s[t] - v + boff[blockIdx.x];
        rowstart[idx] = excl;
        cur[idx] = excl;
    }
}

__global__ __launch_bounds__(256) void fill_kernel(const int* __restrict__ edst,
                                                   int* __restrict__ cur,
                                                   int* __restrict__ eid) {
    const int e = blockIdx.x * 256 + threadIdx.x;
    if (e < NEDGES) {
        const int p = atomicAdd(&cur[edst[e]], 1);
        eid[p] = e;
    }
}

// ---------------- edge MLP via MFMA, bf16, output written at CSR position ----------------
// Thread t's edge is e = eid[p] with p = blockIdx*256 + t; wbuf row index is p, so
// gather_final reads wbuf fully sequentially per node.
// LDS: weights transposed bf16, XOR-swizzled (kb' = kb ^ (row&7), row stride 64 elem):
// both A- and B-fragments are single conflict-free ds_read_b128.
#define LDS_W0 0        // 64 rows x 64  (k 0..7 data, rest zero)
#define LDS_W1 4096     // 64 rows x 64
#define LDS_W2 8192     // 128 rows x 64
#define LDS_ACT 16384   // 4 waves x (64 rows x 64)
__global__ __launch_bounds__(256, 2) void edge_mlp_mfma(
    const float* __restrict__ eemb, const int* __restrict__ eid,
    const float* __restrict__ fw0, const float* __restrict__ fw1,
    const float* __restrict__ fw2,
    unsigned short* __restrict__ wbuf)
{
    __shared__ short lds[32768];   // 64 KB
    const int t = threadIdx.x;
    const int p = blockIdx.x * 256 + t;
    const int e = eid[p];

    // ---- stage weights (transposed, swizzled, bf16) ----
    for (int s = t; s < 512; s += 256) {          // W0t: fw0 is [8][64]
        const int n = s >> 3, kb = s & 7;
        uint4 v = {0u, 0u, 0u, 0u};
        if (kb == 0) {
            unsigned h[8];
            #pragma unroll
            for (int i = 0; i < 8; ++i) h[i] = bf16rne(fw0[i * 64 + n]);
            v.x = h[0] | (h[1] << 16); v.y = h[2] | (h[3] << 16);
            v.z = h[4] | (h[5] << 16); v.w = h[6] | (h[7] << 16);
        }
        *(uint4*)&lds[LDS_W0 + n * 64 + ((kb ^ (n & 7)) * 8)] = v;
    }
    for (int s = t; s < 512; s += 256) {          // W1t: fw1 is [64][64]
        const int n = s >> 3, kb = s & 7;
        unsigned h[8];
        #pragma unroll
        for (int i = 0; i < 8; ++i) h[i] = bf16rne(fw1[(kb * 8 + i) * 64 + n]);
        uint4 v;
        v.x = h[0] | (h[1] << 16); v.y = h[2] | (h[3] << 16);
        v.z = h[4] | (h[5] << 16); v.w = h[6] | (h[7] << 16);
        *(uint4*)&lds[LDS_W1 + n * 64 + ((kb ^ (n & 7)) * 8)] = v;
    }
    for (int s = t; s < 1024; s += 256) {         // W2t: fw2 is [64][128]
        const int n = s >> 3, kb = s & 7;
        unsigned h[8];
        #pragma unroll
        for (int i = 0; i < 8; ++i) h[i] = bf16rne(fw2[(kb * 8 + i) * 128 + n]);
        uint4 v;
        v.x = h[0] | (h[1] << 16); v.y = h[2] | (h[3] << 16);
        v.z = h[4] | (h[5] << 16); v.w = h[6] | (h[7] << 16);
        *(uint4*)&lds[LDS_W2 + n * 64 + ((kb ^ (n & 7)) * 8)] = v;
    }

    // ---- stage X (this thread's edge) into per-wave activation buffer ----
    short* const ab = &lds[LDS_ACT + (t >> 6) * 4096];
    {
        const float4 q0 = *(const float4*)(eemb + (size_t)e * 8);
        const float4 q1 = *(const float4*)(eemb + (size_t)e * 8 + 4);
        uint4 xv;
        xv.x = bf16rne(q0.x) | (bf16rne(q0.y) << 16);
        xv.y = bf16rne(q0.z) | (bf16rne(q0.w) << 16);
        xv.z = bf16rne(q1.x) | (bf16rne(q1.y) << 16);
        xv.w = bf16rne(q1.z) | (bf16rne(q1.w) << 16);
        const int m = t & 63;
        const uint4 zz = {0u, 0u, 0u, 0u};
        *(uint4*)&ab[m * 64 + ((0 ^ (m & 7)) * 8)] = xv;
        *(uint4*)&ab[m * 64 + ((1 ^ (m & 7)) * 8)] = zz;
        *(uint4*)&ab[m * 64 + ((2 ^ (m & 7)) * 8)] = zz;
        *(uint4*)&ab[m * 64 + ((3 ^ (m & 7)) * 8)] = zz;
    }
    __syncthreads();

    const int lane = t & 63;
    const int q = lane >> 4;          // quad
    const int c = lane & 15;          // frag row/col index
    const int sw = c & 7;             // swizzle key: (row&7) == (c&7) since tile offsets %16==0
    const f32x4 zf = {0.f, 0.f, 0.f, 0.f};

    // ---- layer 1: A1 = silu(X @ W0 / sqrt(8)), M=64 N=64 K=32(pad) ----
    f32x4 acc1[4][4];
    #pragma unroll
    for (int mt = 0; mt < 4; ++mt)
        #pragma unroll
        for (int nt = 0; nt < 4; ++nt) acc1[mt][nt] = zf;
    {
        short8 af[4];
        #pragma unroll
        for (int mt = 0; mt < 4; ++mt)
            af[mt] = *(const short8*)&ab[(mt * 16 + c) * 64 + ((q ^ sw) * 8)];
        #pragma unroll
        for (int nt = 0; nt < 4; ++nt) {
            const short8 bf = *(const short8*)&lds[LDS_W0 + (nt * 16 + c) * 64 + ((q ^ sw) * 8)];
            #pragma unroll
            for (int mt = 0; mt < 4; ++mt)
                acc1[mt][nt] = __builtin_amdgcn_mfma_f32_16x16x32_bf16(af[mt], bf, acc1[mt][nt], 0, 0, 0);
        }
    }
    // repack A1 -> ab (silu, bf16)
    const float inv_s8 = 0.35355339059327373f;
    #pragma unroll
    for (int mt = 0; mt < 4; ++mt)
        #pragma unroll
        for (int nt = 0; nt < 4; ++nt) {
            #pragma unroll
            for (int r = 0; r < 4; ++r) {
                const int m = mt * 16 + q * 4 + r;
                const int k = nt * 16 + c;
                const float x = silu_f(acc1[mt][nt][r] * inv_s8);
                ab[m * 64 + (((k >> 3) ^ (m & 7)) * 8) + (k & 7)] = (short)bf16rne(x);
            }
        }

    // ---- layer 2: A2 = silu(A1 @ W1 / 8), M=64 N=64 K=64 ----
    f32x4 acc2[4][4];
    #pragma unroll
    for (int mt = 0; mt < 4; ++mt)
        #pragma unroll
        for (int nt = 0; nt < 4; ++nt) acc2[mt][nt] = zf;
    #pragma unroll
    for (int kt = 0; kt < 2; ++kt) {
        short8 af[4];
        #pragma unroll
        for (int mt = 0; mt < 4; ++mt)
            af[mt] = *(const short8*)&ab[(mt * 16 + c) * 64 + (((kt * 4 + q) ^ sw) * 8)];
        #pragma unroll
        for (int nt = 0; nt < 4; ++nt) {
            const short8 bf = *(const short8*)&lds[LDS_W1 + (nt * 16 + c) * 64 + (((kt * 4 + q) ^ sw) * 8)];
            #pragma unroll
            for (int mt = 0; mt < 4; ++mt)
                acc2[mt][nt] = __builtin_amdgcn_mfma_f32_16x16x32_bf16(af[mt], bf, acc2[mt][nt], 0, 0, 0);
        }
    }
    #pragma unroll
    for (int mt = 0; mt < 4; ++mt)
        #pragma unroll
        for (int nt = 0; nt < 4; ++nt) {
            #pragma unroll
            for (int r = 0; r < 4; ++r) {
                const int m = mt * 16 + q * 4 + r;
                const int k = nt * 16 + c;
                const float x = silu_f(acc2[mt][nt][r] * 0.125f);
                ab[m * 64 + (((k >> 3) ^ (m & 7)) * 8) + (k & 7)] = (short)bf16rne(x);
            }
        }

    // ---- layer 3: W = A2 @ W2 / 8, M=64 N=128 K=64 ----
    f32x4 acc3[4][8];
    #pragma unroll
    for (int mt = 0; mt < 4; ++mt)
        #pragma unroll
        for (int nt = 0; nt < 8; ++nt) acc3[mt][nt] = zf;
    #pragma unroll
    for (int kt = 0; kt < 2; ++kt) {
        short8 af[4];
        #pragma unroll
        for (int mt = 0; mt < 4; ++mt)
            af[mt] = *(const short8*)&ab[(mt * 16 + c) * 64 + (((kt * 4 + q) ^ sw) * 8)];
        #pragma unroll
        for (int nt = 0; nt < 8; ++nt) {
            const short8 bf = *(const short8*)&lds[LDS_W2 + (nt * 16 + c) * 64 + (((kt * 4 + q) ^ sw) * 8)];
            #pragma unroll
            for (int mt = 0; mt < 4; ++mt)
                acc3[mt][nt] = __builtin_amdgcn_mfma_f32_16x16x32_bf16(af[mt], bf, acc3[mt][nt], 0, 0, 0);
        }
    }
    // store w (bf16) at CSR position
    const int pbase = blockIdx.x * 256 + (t >> 6) * 64;
    #pragma unroll
    for (int mt = 0; mt < 4; ++mt)
        #pragma unroll
        for (int nt = 0; nt < 8; ++nt) {
            #pragma unroll
            for (int r = 0; r < 4; ++r) {
                const int pp = pbase + mt * 16 + q * 4 + r;
                const int n = nt * 16 + c;
                wbuf[(size_t)pp * 128 + n] = (unsigned short)bf16rne(acc3[mt][nt][r] * 0.125f);
            }
        }
}

// ---------------- gather + tensor product + lin2 + gate + output ----------------
__global__ __launch_bounds__(256) void gather_final_kernel(
    const float* __restrict__ esh, const int* __restrict__ esrc,
    const int* __restrict__ eid, const int* __restrict__ rowstart,
    const int* __restrict__ cnt, const unsigned short* __restrict__ wbuf,
    const float* __restrict__ h0, const float* __restrict__ h1,
    const float* __restrict__ scs, const float* __restrict__ scg,
    const float* __restrict__ scv,
    const float* __restrict__ l2w0, const float* __restrict__ l2w1,
    float* __restrict__ out)
{
    __shared__ float wL[8][128];
    __shared__ float hL[8][128];   // [0:32) = h0[src], [32:128) = h1[src]
    __shared__ float yL[8][4];
    __shared__ int   srcL[8];
    __shared__ float sV[256];
    __shared__ float gL[32];

    const int n = blockIdx.x;
    const int j = threadIdx.x;
    const int start = rowstart[n];
    const int deg = cnt[n];

    int cls, u = 0, m = 0;
    if (j < 32)        { cls = 0; u = j; }
    else if (j < 64)   { cls = 1; u = j - 32; }
    else if (j < 160)  { cls = 2; const int i = j - 64;  u = i / 3; m = i - 3 * u; }
    else               { cls = 3; const int i = j - 160; u = i / 3; m = i - 3 * u; }

    float acc = 0.0f;
    for (int base = 0; base < deg; base += 8) {
        const int nk = min(8, deg - base);
        __syncthreads();
        if (j < nk) {
            const int ek = eid[start + base + j];
            *(float4*)yL[j] = *(const float4*)(esh + (size_t)ek * 4);
            srcL[j] = esrc[ek];
        }
        __syncthreads();
        {   // bulk stage: 256 threads x 4 elements = 8 edges x 128
            const int i4 = j * 4;
            const int k = i4 >> 7;
            const int c = i4 & 127;
            if (k < nk) {
                const int pp = start + base + k;   // wbuf is CSR-ordered: sequential read
                const ushort4 wv = *(const ushort4*)(wbuf + (size_t)pp * 128 + c);
                wL[k][c+0] = bf2f(wv.x); wL[k][c+1] = bf2f(wv.y);
                wL[k][c+2] = bf2f(wv.z); wL[k][c+3] = bf2f(wv.w);
                const int src = srcL[k];
                const float4 hv = (c < 32) ? *(const float4*)(h0 + src * 32 + c)
                                           : *(const float4*)(h1 + src * 96 + (c - 32));
                *(float4*)&hL[k][c] = hv;
            }
        }
        __syncthreads();
        if (cls == 0) {
            for (int k = 0; k < nk; ++k)
                acc += wL[k][u] * hL[k][u] * yL[k][0];
        } else if (cls == 1) {
            for (int k = 0; k < nk; ++k) {
                const float d = hL[k][32 + u*3 + 0] * yL[k][1]
                              + hL[k][32 + u*3 + 1] * yL[k][2]
                              + hL[k][32 + u*3 + 2] * yL[k][3];
                acc += wL[k][96 + u] * d;
            }
        } else if (cls == 2) {
            for (int k = 0; k < nk; ++k)
                acc += wL[k][32 + u] * hL[k][u] * yL[k][1 + m];
        } else {
            for (int k = 0; k < nk; ++k)
                acc += wL[k][64 + u] * yL[k][0] * hL[k][32 + u*3 + m];
        }
    }
    __syncthreads();
    const float cs  = 0.0625f;                 // 1/N_NEIGH
    const float cs3 = 0.03608439182435161f;    // cs / sqrt(3)
    sV[j] = acc * ((cls == 1) ? cs3 : cs);
    __syncthreads();

    const float l2 = 0.125f; // 1/sqrt(64)
    if (j < 32) {
        float a = 0.0f;
        #pragma unroll
        for (int k = 0; k < 64; ++k) a += sV[k] * l2w0[k * 64 + 32 + j];
        gL[j] = silu_f(a * l2 + scg[n * 32 + j]);
    }
    __syncthreads();
    if (j < 32) {
        float a = 0.0f;
        #pragma unroll
        for (int k = 0; k < 64; ++k) a += sV[k] * l2w0[k * 64 + j];
        out[n * 128 + j] = silu_f(a * l2 + scs[n * 32 + j]);
    } else if (j < 128) {
        const int i = j - 32;
        const int v = i / 3;
        const int mm = i - 3 * v;
        float a = 0.0f;
        #pragma unroll
        for (int uu = 0; uu < 64; ++uu) a += sV[64 + uu * 3 + mm] * l2w1[uu * 32 + v];
        out[n * 128 + 32 + i] = gL[v] * (a * l2 + scv[n * 96 + i]);
    }
}

extern "C" void kernel_launch(void* const* d_in, const int* in_sizes, int n_in,
                              void* d_out, int out_size, void* d_ws, size_t ws_size,
                              hipStream_t stream) {
    const float* nf   = (const float*)d_in[0];
    const float* za   = (const float*)d_in[1];
    const float* esh  = (const float*)d_in[2];
    const float* eemb = (const float*)d_in[3];
    const float* l1w0 = (const float*)d_in[4];
    const float* l1w1 = (const float*)d_in[5];
    const float* fw0  = (const float*)d_in[6];
    const float* fw1  = (const float*)d_in[7];
    const float* fw2  = (const float*)d_in[8];
    const float* wS   = (const float*)d_in[9];
    const float* wG   = (const float*)d_in[10];
    const float* wV   = (const float*)d_in[11];
    const float* l2w0 = (const float*)d_in[12];
    const float* l2w1 = (const float*)d_in[13];
    const int* esrc   = (const int*)d_in[14];
    const int* edst   = (const int*)d_in[15];
    float* out = (float*)d_out;

    // EXACT round-2 workspace layout (266.2 MB total, known to fit ws_size)
    float* ws  = (float*)d_ws;
    float* h0  = ws;                     // 1,600,000 floats
    float* h1  = h0 + 1600000;           // 4,800,000
    float* scs = h1 + 4800000;           // 1,600,000
    float* scg = scs + 1600000;          // 1,600,000
    float* scv = scg + 1600000;          // 4,800,000
    int*   cnt      = (int*)(scv + 4800000); // 50176
    int*   rowstart = cnt + 50176;           // 50176
    int*   cur      = rowstart + 50176;      // 50176
    int*   bsum     = cur + 50176;           // 256
    int*   boff     = bsum + 256;            // 256
    int*   eid      = boff + 256;            // 800,000
    unsigned short* wbuf = (unsigned short*)(eid + 800000); // 800000*128 bf16 = 204.8 MB

    hipMemsetAsync(cnt, 0, 50176 * sizeof(int), stream);
    node_prep_kernel<<<NNODES, 128, 0, stream>>>(nf, l1w0, l1w1, h0, h1);
    sc_scalar_kernel<<<391, 256, 0, stream>>>(nf, za, wS, wG, scs, scg);
    sc_vec_kernel<<<586, 256, 0, stream>>>(nf, za, wV, scv);
    hist_kernel<<<3125, 256, 0, stream>>>(edst, cnt);
    scan_a_kernel<<<NCHUNK, 256, 0, stream>>>(cnt, bsum);
    scan_b_kernel<<<1, 256, 0, stream>>>(bsum, boff);
    scan_c_kernel<<<NCHUNK, 256, 0, stream>>>(cnt, boff, rowstart, cur);
    fill_kernel<<<3125, 256, 0, stream>>>(edst, cur, eid);
    edge_mlp_mfma<<<3125, 256, 0, stream>>>(eemb, eid, fw0, fw1, fw2, wbuf);
    gather_final_kernel<<<NNODES, 256, 0, stream>>>(esh, esrc, eid, rowstart, cnt,
                                                    wbuf, h0, h1, scs, scg, scv,
                                                    l2w0, l2w1, out);
}

// Round 5
// 819.135 us; speedup vs baseline: 13.4555x; 1.0795x over previous
//
#include <hip/hip_runtime.h>

#define NNODES 50000
#define NEDGES 800000
#define NCHUNK 196   // ceil(50000/256)

typedef __attribute__((ext_vector_type(8))) short short8;
typedef __attribute__((ext_vector_type(4))) float f32x4;
typedef __attribute__((ext_vector_type(4))) unsigned int u32x4;

__device__ __forceinline__ float silu_f(float x) {
    return __fdividef(x, 1.0f + __expf(-x));
}
__device__ __forceinline__ unsigned bf16rne(float x) {
    unsigned u = __float_as_uint(x);
    return (u + 0x7FFFu + ((u >> 16) & 1u)) >> 16;
}
__device__ __forceinline__ float bf2f(unsigned short h) {
    return __uint_as_float(((unsigned)h) << 16);
}

// ---------------- h0/h1 (bf16 out) ----------------
__global__ __launch_bounds__(128) void node_prep_kernel(
    const float* __restrict__ nf, const float* __restrict__ w0,
    const float* __restrict__ w1, unsigned short* __restrict__ h0b,
    unsigned short* __restrict__ h1b)
{
    __shared__ float row[128];
    const int n = blockIdx.x;
    const int j = threadIdx.x;
    row[j] = nf[n * 128 + j];
    __syncthreads();
    const float l1 = 0.17677669529663687f; // 1/sqrt(32)
    if (j < 32) {
        float acc = 0.0f;
        #pragma unroll
        for (int u = 0; u < 32; ++u) acc += row[u] * w0[u * 32 + j];
        h0b[n * 32 + j] = (unsigned short)bf16rne(acc * l1);
    } else {
        const int i = j - 32;
        const int v = i / 3;
        const int m = i - 3 * v;
        float acc = 0.0f;
        #pragma unroll
        for (int u = 0; u < 32; ++u) acc += row[32 + u * 3 + m] * w1[u * 32 + v];
        h1b[n * 96 + i] = (unsigned short)bf16rne(acc * l1);
    }
}

// ---------------- self-connection scalar+gate
__global__ __launch_bounds__(256) void sc_scalar_kernel(
    const float* __restrict__ nf, const float* __restrict__ za,
    const float* __restrict__ wS, const float* __restrict__ wG,
    float* __restrict__ scs, float* __restrict__ scg)
{
    const int t = blockIdx.x * 256 + threadIdx.x;
    const int lane = t & 63;
    const int h = __builtin_amdgcn_readfirstlane((t >> 6) & 1);  // wave-uniform -> s_load weights
    const int n = (t >> 7) * 64 + lane;
    if (n >= NNODES) return;
    const float* x0p = nf + n * 128;
    const float* zp  = za + n * 16;
    const float* bS0 = wS + h * 16;
    const float* bG0 = wG + h * 16;
    float accS[16], accG[16];
    #pragma unroll
    for (int w = 0; w < 16; ++w) { accS[w] = 0.0f; accG[w] = 0.0f; }
    for (int u = 0; u < 32; ++u) {
        const float xu = x0p[u];
        for (int v = 0; v < 16; ++v) {
            const float p = xu * zp[v];
            const float* bS = bS0 + (u * 16 + v) * 32;
            const float* bG = bG0 + (u * 16 + v) * 32;
            #pragma unroll
            for (int w = 0; w < 16; w += 4) {
                const float4 qs = *(const float4*)(bS + w);
                const float4 qg = *(const float4*)(bG + w);
                accS[w+0] += p * qs.x; accS[w+1] += p * qs.y;
                accS[w+2] += p * qs.z; accS[w+3] += p * qs.w;
                accG[w+0] += p * qg.x; accG[w+1] += p * qg.y;
                accG[w+2] += p * qg.z; accG[w+3] += p * qg.w;
            }
        }
    }
    const float scn = 0.04419417382415922f; // 1/sqrt(512)
    #pragma unroll
    for (int w = 0; w < 16; ++w) {
        scs[n * 32 + h * 16 + w] = accS[w] * scn;
        scg[n * 32 + h * 16 + w] = accG[w] * scn;
    }
}

// ---------------- self-connection vector
__global__ __launch_bounds__(256) void sc_vec_kernel(
    const float* __restrict__ nf, const float* __restrict__ za,
    const float* __restrict__ wV, float* __restrict__ scv)
{
    const int t = blockIdx.x * 256 + threadIdx.x;
    if (t >= NNODES * 3) return;
    const int n = t / 3;
    const int m = t - 3 * n;
    const float* x1p = nf + n * 128 + 32 + m;
    const float* zp  = za + n * 16;
    float acc[32];
    #pragma unroll
    for (int w = 0; w < 32; ++w) acc[w] = 0.0f;
    for (int u = 0; u < 32; ++u) {
        const float xu = x1p[u * 3];
        for (int v = 0; v < 16; ++v) {
            const float p = xu * zp[v];
            const float* bV = wV + (u * 16 + v) * 32;  // uniform address
            #pragma unroll
            for (int w = 0; w < 32; w += 4) {
                const float4 q = *(const float4*)(bV + w);
                acc[w+0] += p * q.x; acc[w+1] += p * q.y;
                acc[w+2] += p * q.z; acc[w+3] += p * q.w;
            }
        }
    }
    const float scn = 0.04419417382415922f;
    #pragma unroll
    for (int w = 0; w < 32; ++w) scv[n * 96 + w * 3 + m] = acc[w] * scn;
}

// ---------------- CSR build ----------------
__global__ __launch_bounds__(256) void hist_kernel(const int* __restrict__ edst,
                                                   int* __restrict__ cnt) {
    const int e = blockIdx.x * 256 + threadIdx.x;
    if (e < NEDGES) atomicAdd(&cnt[edst[e]], 1);
}

__global__ __launch_bounds__(256) void scan_a_kernel(const int* __restrict__ cnt,
                                                     int* __restrict__ bsum) {
    __shared__ int s[256];
    const int t = threadIdx.x;
    const int idx = blockIdx.x * 256 + t;
    s[t] = (idx < NNODES) ? cnt[idx] : 0;
    __syncthreads();
    for (int off = 128; off > 0; off >>= 1) {
        if (t < off) s[t] += s[t + off];
        __syncthreads();
    }
    if (t == 0) bsum[blockIdx.x] = s[0];
}

__global__ __launch_bounds__(256) void scan_b_kernel(const int* __restrict__ bsum,
                                                     int* __restrict__ boff) {
    __shared__ int s[256];
    const int t = threadIdx.x;
    const int v = (t < NCHUNK) ? bsum[t] : 0;
    s[t] = v;
    __syncthreads();
    for (int off = 1; off < 256; off <<= 1) {
        int x = (t >= off) ? s[t - off] : 0;
        __syncthreads();
        s[t] += x;
        __syncthreads();
    }
    if (t < NCHUNK) boff[t] = s[t] - v;   // exclusive
}

__global__ __launch_bounds__(256) void scan_c_kernel(const int* __restrict__ cnt,
                                                     const int* __restrict__ boff,
                                                     int* __restrict__ rowstart,
                                                     int* __restrict__ cur) {
    __shared__ int s[256];
    const int t = threadIdx.x;
    const int idx = blockIdx.x * 256 + t;
    const int v = (idx < NNODES) ? cnt[idx] : 0;
    s[t] = v;
    __syncthreads();
    for (int off = 1; off < 256; off <<= 1) {
        int x = (t >= off) ? s[t - off] : 0;
        __syncthreads();
        s[t] += x;
        __syncthreads();
    }
    if (idx < NNODES) {
        const int excl = s[t] - v + boff[blockIdx.x];
        rowstart[idx] = excl;
        cur[idx] = excl;
    }
}

// fill: also permute esh (bf16) and esrc into CSR order so gather has no indirection
__global__ __launch_bounds__(256) void fill_kernel(const int* __restrict__ edst,
                                                   const int* __restrict__ esrc,
                                                   const float* __restrict__ esh,
                                                   int* __restrict__ cur,
                                                   int* __restrict__ eid,
                                                   int* __restrict__ srcperm,
                                                   unsigned short* __restrict__ yperm) {
    const int e = blockIdx.x * 256 + threadIdx.x;
    if (e < NEDGES) {
        const int p = atomicAdd(&cur[edst[e]], 1);
        eid[p] = e;
        srcperm[p] = esrc[e];
        const float4 y = *(const float4*)(esh + (size_t)e * 4);
        ushort4 yb;
        yb.x = (unsigned short)bf16rne(y.x);
        yb.y = (unsigned short)bf16rne(y.y);
        yb.z = (unsigned short)bf16rne(y.z);
        yb.w = (unsigned short)bf16rne(y.w);
        *(ushort4*)(yperm + (size_t)p * 4) = yb;
    }
}

// ---------------- edge MLP via MFMA, bf16, CSR-position output, PERMUTED row layout ----
// wbuf row p stores comp n at short index (n&15)*8 + (n>>4): a lane's 8 C-layout values
// (nt=0..7, fixed c) are contiguous -> single 16B nontemporal store (16 stores/lane).
#define LDS_W0 0        // 64 rows x 64  (k 0..7 data, rest zero)
#define LDS_W1 4096     // 64 rows x 64
#define LDS_W2 8192     // 128 rows x 64
#define LDS_ACT 16384   // 4 waves x (64 rows x 64)
__global__ __launch_bounds__(256, 2) void edge_mlp_mfma(
    const float* __restrict__ eemb, const int* __restrict__ eid,
    const float* __restrict__ fw0, const float* __restrict__ fw1,
    const float* __restrict__ fw2,
    unsigned short* __restrict__ wbuf)
{
    __shared__ short lds[32768];   // 64 KB
    const int t = threadIdx.x;
    const int p = blockIdx.x * 256 + t;
    const int e = eid[p];

    // ---- stage weights (transposed, swizzled, bf16) ----
    for (int s = t; s < 512; s += 256) {          // W0t: fw0 is [8][64]
        const int n = s >> 3, kb = s & 7;
        uint4 v = {0u, 0u, 0u, 0u};
        if (kb == 0) {
            unsigned h[8];
            #pragma unroll
            for (int i = 0; i < 8; ++i) h[i] = bf16rne(fw0[i * 64 + n]);
            v.x = h[0] | (h[1] << 16); v.y = h[2] | (h[3] << 16);
            v.z = h[4] | (h[5] << 16); v.w = h[6] | (h[7] << 16);
        }
        *(uint4*)&lds[LDS_W0 + n * 64 + ((kb ^ (n & 7)) * 8)] = v;
    }
    for (int s = t; s < 512; s += 256) {          // W1t: fw1 is [64][64]
        const int n = s >> 3, kb = s & 7;
        unsigned h[8];
        #pragma unroll
        for (int i = 0; i < 8; ++i) h[i] = bf16rne(fw1[(kb * 8 + i) * 64 + n]);
        uint4 v;
        v.x = h[0] | (h[1] << 16); v.y = h[2] | (h[3] << 16);
        v.z = h[4] | (h[5] << 16); v.w = h[6] | (h[7] << 16);
        *(uint4*)&lds[LDS_W1 + n * 64 + ((kb ^ (n & 7)) * 8)] = v;
    }
    for (int s = t; s < 1024; s += 256) {         // W2t: fw2 is [64][128]
        const int n = s >> 3, kb = s & 7;
        unsigned h[8];
        #pragma unroll
        for (int i = 0; i < 8; ++i) h[i] = bf16rne(fw2[(kb * 8 + i) * 128 + n]);
        uint4 v;
        v.x = h[0] | (h[1] << 16); v.y = h[2] | (h[3] << 16);
        v.z = h[4] | (h[5] << 16); v.w = h[6] | (h[7] << 16);
        *(uint4*)&lds[LDS_W2 + n * 64 + ((kb ^ (n & 7)) * 8)] = v;
    }

    // ---- stage X into per-wave activation buffer ----
    short* const ab = &lds[LDS_ACT + (t >> 6) * 4096];
    {
        const float4 q0 = *(const float4*)(eemb + (size_t)e * 8);
        const float4 q1 = *(const float4*)(eemb + (size_t)e * 8 + 4);
        uint4 xv;
        xv.x = bf16rne(q0.x) | (bf16rne(q0.y) << 16);
        xv.y = bf16rne(q0.z) | (bf16rne(q0.w) << 16);
        xv.z = bf16rne(q1.x) | (bf16rne(q1.y) << 16);
        xv.w = bf16rne(q1.z) | (bf16rne(q1.w) << 16);
        const int m = t & 63;
        const uint4 zz = {0u, 0u, 0u, 0u};
        *(uint4*)&ab[m * 64 + ((0 ^ (m & 7)) * 8)] = xv;
        *(uint4*)&ab[m * 64 + ((1 ^ (m & 7)) * 8)] = zz;
        *(uint4*)&ab[m * 64 + ((2 ^ (m & 7)) * 8)] = zz;
        *(uint4*)&ab[m * 64 + ((3 ^ (m & 7)) * 8)] = zz;
    }
    __syncthreads();

    const int lane = t & 63;
    const int q = lane >> 4;          // quad
    const int c = lane & 15;          // frag row/col index
    const int sw = c & 7;
    const f32x4 zf = {0.f, 0.f, 0.f, 0.f};

    // ---- layer 1: A1 = silu(X @ W0 / sqrt(8)) ----
    f32x4 acc1[4][4];
    #pragma unroll
    for (int mt = 0; mt < 4; ++mt)
        #pragma unroll
        for (int nt = 0; nt < 4; ++nt) acc1[mt][nt] = zf;
    {
        short8 af[4];
        #pragma unroll
        for (int mt = 0; mt < 4; ++mt)
            af[mt] = *(const short8*)&ab[(mt * 16 + c) * 64 + ((q ^ sw) * 8)];
        #pragma unroll
        for (int nt = 0; nt < 4; ++nt) {
            const short8 bf = *(const short8*)&lds[LDS_W0 + (nt * 16 + c) * 64 + ((q ^ sw) * 8)];
            #pragma unroll
            for (int mt = 0; mt < 4; ++mt)
                acc1[mt][nt] = __builtin_amdgcn_mfma_f32_16x16x32_bf16(af[mt], bf, acc1[mt][nt], 0, 0, 0);
        }
    }
    const float inv_s8 = 0.35355339059327373f;
    #pragma unroll
    for (int mt = 0; mt < 4; ++mt)
        #pragma unroll
        for (int nt = 0; nt < 4; ++nt) {
            #pragma unroll
            for (int r = 0; r < 4; ++r) {
                const int m = mt * 16 + q * 4 + r;
                const int k = nt * 16 + c;
                const float x = silu_f(acc1[mt][nt][r] * inv_s8);
                ab[m * 64 + (((k >> 3) ^ (m & 7)) * 8) + (k & 7)] = (short)bf16rne(x);
            }
        }

    // ---- layer 2: A2 = silu(A1 @ W1 / 8) ----
    f32x4 acc2[4][4];
    #pragma unroll
    for (int mt = 0; mt < 4; ++mt)
        #pragma unroll
        for (int nt = 0; nt < 4; ++nt) acc2[mt][nt] = zf;
    #pragma unroll
    for (int kt = 0; kt < 2; ++kt) {
        short8 af[4];
        #pragma unroll
        for (int mt = 0; mt < 4; ++mt)
            af[mt] = *(const short8*)&ab[(mt * 16 + c) * 64 + (((kt * 4 + q) ^ sw) * 8)];
        #pragma unroll
        for (int nt = 0; nt < 4; ++nt) {
            const short8 bf = *(const short8*)&lds[LDS_W1 + (nt * 16 + c) * 64 + (((kt * 4 + q) ^ sw) * 8)];
            #pragma unroll
            for (int mt = 0; mt < 4; ++mt)
                acc2[mt][nt] = __builtin_amdgcn_mfma_f32_16x16x32_bf16(af[mt], bf, acc2[mt][nt], 0, 0, 0);
        }
    }
    #pragma unroll
    for (int mt = 0; mt < 4; ++mt)
        #pragma unroll
        for (int nt = 0; nt < 4; ++nt) {
            #pragma unroll
            for (int r = 0; r < 4; ++r) {
                const int m = mt * 16 + q * 4 + r;
                const int k = nt * 16 + c;
                const float x = silu_f(acc2[mt][nt][r] * 0.125f);
                ab[m * 64 + (((k >> 3) ^ (m & 7)) * 8) + (k & 7)] = (short)bf16rne(x);
            }
        }

    // ---- layer 3: W = A2 @ W2 / 8 ----
    f32x4 acc3[4][8];
    #pragma unroll
    for (int mt = 0; mt < 4; ++mt)
        #pragma unroll
        for (int nt = 0; nt < 8; ++nt) acc3[mt][nt] = zf;
    #pragma unroll
    for (int kt = 0; kt < 2; ++kt) {
        short8 af[4];
        #pragma unroll
        for (int mt = 0; mt < 4; ++mt)
            af[mt] = *(const short8*)&ab[(mt * 16 + c) * 64 + (((kt * 4 + q) ^ sw) * 8)];
        #pragma unroll
        for (int nt = 0; nt < 8; ++nt) {
            const short8 bf = *(const short8*)&lds[LDS_W2 + (nt * 16 + c) * 64 + (((kt * 4 + q) ^ sw) * 8)];
            #pragma unroll
            for (int mt = 0; mt < 4; ++mt)
                acc3[mt][nt] = __builtin_amdgcn_mfma_f32_16x16x32_bf16(af[mt], bf, acc3[mt][nt], 0, 0, 0);
        }
    }
    // packed store: lane's 8 comps (nt=0..7) of edge pp -> 16 B at short offset c*8
    const int pbase = blockIdx.x * 256 + (t >> 6) * 64;
    #pragma unroll
    for (int mt = 0; mt < 4; ++mt)
        #pragma unroll
        for (int r = 0; r < 4; ++r) {
            const int pp = pbase + mt * 16 + q * 4 + r;
            u32x4 v;
            v.x = bf16rne(acc3[mt][0][r] * 0.125f) | (bf16rne(acc3[mt][1][r] * 0.125f) << 16);
            v.y = bf16rne(acc3[mt][2][r] * 0.125f) | (bf16rne(acc3[mt][3][r] * 0.125f) << 16);
            v.z = bf16rne(acc3[mt][4][r] * 0.125f) | (bf16rne(acc3[mt][5][r] * 0.125f) << 16);
            v.w = bf16rne(acc3[mt][6][r] * 0.125f) | (bf16rne(acc3[mt][7][r] * 0.125f) << 16);
            __builtin_nontemporal_store(v, (u32x4*)(wbuf + (size_t)pp * 128 + c * 8));
        }
}

// ---------------- gather + tensor product + lin2 + gate + output ----------------
// wbuf rows are PERMUTED: comp n lives at short index (n&15)*8 + (n>>4).
#define KE 16
__global__ __launch_bounds__(256) void gather_final_kernel(
    const unsigned short* __restrict__ yperm, const int* __restrict__ srcperm,
    const int* __restrict__ rowstart, const int* __restrict__ cnt,
    const unsigned short* __restrict__ wbuf,
    const unsigned short* __restrict__ h0b, const unsigned short* __restrict__ h1b,
    const float* __restrict__ scs, const float* __restrict__ scg,
    const float* __restrict__ scv,
    const float* __restrict__ l2w0, const float* __restrict__ l2w1,
    float* __restrict__ out)
{
    __shared__ float wP[KE][128];   // permuted comp order
    __shared__ float hL[KE][128];   // [0:32) h0 row, [32:128) h1 row
    __shared__ float yL[KE][4];
    __shared__ int   srcL[KE];
    __shared__ float sV[256];
    __shared__ float gL[32];

    const int n = blockIdx.x;
    const int j = threadIdx.x;
    const int start = rowstart[n];
    const int deg = cnt[n];

    int cls, u = 0, m = 0;
    if (j < 32)        { cls = 0; u = j; }
    else if (j < 64)   { cls = 1; u = j - 32; }
    else if (j < 160)  { cls = 2; const int i = j - 64;  u = i / 3; m = i - 3 * u; }
    else               { cls = 3; const int i = j - 160; u = i / 3; m = i - 3 * u; }
    // permuted w index for this thread's component
    const int comp = (cls == 0) ? u : (cls == 1) ? (96 + u) : (cls == 2) ? (32 + u) : (64 + u);
    const int wqi = (comp & 15) * 8 + (comp >> 4);

    float acc = 0.0f;
    for (int base = 0; base < deg; base += KE) {
        const int nk = min(KE, deg - base);
        __syncthreads();
        if (j < nk) {
            const int pp = start + base + j;
            const ushort4 yb = *(const ushort4*)(yperm + (size_t)pp * 4);
            yL[j][0] = bf2f(yb.x); yL[j][1] = bf2f(yb.y);
            yL[j][2] = bf2f(yb.z); yL[j][3] = bf2f(yb.w);
            srcL[j] = srcperm[pp];
        }
        __syncthreads();
        {   // bulk stage: 256 threads x 8 shorts = 2048 = 16 edges x 128
            const int i8 = j * 8;
            const int k = i8 >> 7;
            const int c8 = i8 & 127;
            if (k < nk) {
                const int pp = start + base + k;   // sequential wbuf read, nontemporal
                const u32x4 wv = __builtin_nontemporal_load(
                    (const u32x4*)(wbuf + (size_t)pp * 128 + c8));
                wP[k][c8+0] = bf2f((unsigned short)(wv.x & 0xffff));
                wP[k][c8+1] = bf2f((unsigned short)(wv.x >> 16));
                wP[k][c8+2] = bf2f((unsigned short)(wv.y & 0xffff));
                wP[k][c8+3] = bf2f((unsigned short)(wv.y >> 16));
                wP[k][c8+4] = bf2f((unsigned short)(wv.z & 0xffff));
                wP[k][c8+5] = bf2f((unsigned short)(wv.z >> 16));
                wP[k][c8+6] = bf2f((unsigned short)(wv.w & 0xffff));
                wP[k][c8+7] = bf2f((unsigned short)(wv.w >> 16));
                const int src = srcL[k];
                const ushort4* hp = (c8 < 32)
                    ? (const ushort4*)(h0b + (size_t)src * 32 + c8)
                    : (const ushort4*)(h1b + (size_t)src * 96 + (c8 - 32));
                const ushort4 hv0 = hp[0];
                const ushort4 hv1 = hp[1];
                hL[k][c8+0] = bf2f(hv0.x); hL[k][c8+1] = bf2f(hv0.y);
                hL[k][c8+2] = bf2f(hv0.z); hL[k][c8+3] = bf2f(hv0.w);
                hL[k][c8+4] = bf2f(hv1.x); hL[k][c8+5] = bf2f(hv1.y);
                hL[k][c8+6] = bf2f(hv1.z); hL[k][c8+7] = bf2f(hv1.w);
            }
        }
        __syncthreads();
        if (cls == 0) {
            for (int k = 0; k < nk; ++k)
                acc += wP[k][wqi] * hL[k][u] * yL[k][0];
        } else if (cls == 1) {
            for (int k = 0; k < nk; ++k) {
                const float d = hL[k][32 + u*3 + 0] * yL[k][1]
                              + hL[k][32 + u*3 + 1] * yL[k][2]
                              + hL[k][32 + u*3 + 2] * yL[k][3];
                acc += wP[k][wqi] * d;
            }
        } else if (cls == 2) {
            for (int k = 0; k < nk; ++k)
                acc += wP[k][wqi] * hL[k][u] * yL[k][1 + m];
        } else {
            for (int k = 0; k < nk; ++k)
                acc += wP[k][wqi] * yL[k][0] * hL[k][32 + u*3 + m];
        }
    }
    __syncthreads();
    const float cs  = 0.0625f;                 // 1/N_NEIGH
    const float cs3 = 0.03608439182435161f;    // cs / sqrt(3)
    sV[j] = acc * ((cls == 1) ? cs3 : cs);
    __syncthreads();

    const float l2 = 0.125f; // 1/sqrt(64)
    if (j < 32) {
        float a = 0.0f;
        #pragma unroll
        for (int k = 0; k < 64; ++k) a += sV[k] * l2w0[k * 64 + 32 + j];
        gL[j] = silu_f(a * l2 + scg[n * 32 + j]);
    }
    __syncthreads();
    if (j < 32) {
        float a = 0.0f;
        #pragma unroll
        for (int k = 0; k < 64; ++k) a += sV[k] * l2w0[k * 64 + j];
        out[n * 128 + j] = silu_f(a * l2 + scs[n * 32 + j]);
    } else if (j < 128) {
        const int i = j - 32;
        const int v = i / 3;
        const int mm = i - 3 * v;
        float a = 0.0f;
        #pragma unroll
        for (int uu = 0; uu < 64; ++uu) a += sV[64 + uu * 3 + mm] * l2w1[uu * 32 + v];
        out[n * 128 + 32 + i] = gL[v] * (a * l2 + scv[n * 96 + i]);
    }
}

extern "C" void kernel_launch(void* const* d_in, const int* in_sizes, int n_in,
                              void* d_out, int out_size, void* d_ws, size_t ws_size,
                              hipStream_t stream) {
    const float* nf   = (const float*)d_in[0];
    const float* za   = (const float*)d_in[1];
    const float* esh  = (const float*)d_in[2];
    const float* eemb = (const float*)d_in[3];
    const float* l1w0 = (const float*)d_in[4];
    const float* l1w1 = (const float*)d_in[5];
    const float* fw0  = (const float*)d_in[6];
    const float* fw1  = (const float*)d_in[7];
    const float* fw2  = (const float*)d_in[8];
    const float* wS   = (const float*)d_in[9];
    const float* wG   = (const float*)d_in[10];
    const float* wV   = (const float*)d_in[11];
    const float* l2w0 = (const float*)d_in[12];
    const float* l2w1 = (const float*)d_in[13];
    const int* esrc   = (const int*)d_in[14];
    const int* edst   = (const int*)d_in[15];
    float* out = (float*)d_out;

    // Workspace layout: 263.0 MB total (< round-2's proven 266.2 MB)
    float* ws  = (float*)d_ws;
    float* scs = ws;                         // 1,600,000 f32
    float* scg = scs + 1600000;              // 1,600,000 f32
    float* scv = scg + 1600000;              // 4,800,000 f32
    unsigned short* h0b = (unsigned short*)(scv + 4800000); // 1,600,000 bf16
    unsigned short* h1b = h0b + 1600000;     // 4,800,000 bf16
    int*   cnt      = (int*)(h1b + 4800000); // 50176
    int*   rowstart = cnt + 50176;           // 50176
    int*   cur      = rowstart + 50176;      // 50176
    int*   bsum     = cur + 50176;           // 256
    int*   boff     = bsum + 256;            // 256
    int*   eid      = boff + 256;            // 800,000
    int*   srcperm  = eid + 800000;          // 800,000
    unsigned short* yperm = (unsigned short*)(srcperm + 800000); // 3,200,000 bf16
    unsigned short* wbuf  = yperm + 3200000; // 102,400,000 bf16 = 204.8 MB

    hipMemsetAsync(cnt, 0, 50176 * sizeof(int), stream);
    node_prep_kernel<<<NNODES, 128, 0, stream>>>(nf, l1w0, l1w1, h0b, h1b);
    sc_scalar_kernel<<<391, 256, 0, stream>>>(nf, za, wS, wG, scs, scg);
    sc_vec_kernel<<<586, 256, 0, stream>>>(nf, za, wV, scv);
    hist_kernel<<<3125, 256, 0, stream>>>(edst, cnt);
    scan_a_kernel<<<NCHUNK, 256, 0, stream>>>(cnt, bsum);
    scan_b_kernel<<<1, 256, 0, stream>>>(bsum, boff);
    scan_c_kernel<<<NCHUNK, 256, 0, stream>>>(cnt, boff, rowstart, cur);
    fill_kernel<<<3125, 256, 0, stream>>>(edst, esrc, esh, cur, eid, srcperm, yperm);
    edge_mlp_mfma<<<3125, 256, 0, stream>>>(eemb, eid, fw0, fw1, fw2, wbuf);
    gather_final_kernel<<<NNODES, 256, 0, stream>>>(yperm, srcperm, rowstart, cnt,
                                                    wbuf, h0b, h1b, scs, scg, scv,
                                                    l2w0, l2w1, out);
}